// Round 9
// baseline (857.732 us; speedup 1.0000x reference)
//
#include <hip/hip_runtime.h>
#include <hip/hip_bf16.h>

// Problem constants (from reference)
#define S_LEN   2048
#define BATCH   4
#define IN_DIM  64
#define H_DIM   1024
#define DFF_DIM 1024
#define OUT_DIM 64
#define NLAYER  3
#define NHEADS  4
#define DHEAD   256     // H / NHEAD
#define WIN     4       // banded window: j in [i-4, i]
#define ROWS    (S_LEN*BATCH)  // 8192 flattened (s,b) rows, row = s*B + b
#define QKV_LD  (3*H_DIM)      // 3072

// Established facts (rounds 0-8):
//  - inputs fp32, OUTPUT fp32; seq-major rows (row = s*B+b), window stride B.
//  - r7: 797 us (single-buffer + swizzle, conflicts 0). r8 dbuf NEUTRAL
//    (798; QKV 78->82) => m99/m100 replicated: the 2-barrier K-loop is
//    structurally latency-bound; source-level GEMM tuning is exhausted.
// This round: (1) revert GEMM to r7 single-buffer; (2) LDS-staged attention
// (k/v read once, not 5x); (3) residual-add fused into Wo/W2 epilogues so
// LN reads a single stream.

typedef __bf16 bf16x8 __attribute__((ext_vector_type(8)));
typedef float  f32x4  __attribute__((ext_vector_type(4)));

__device__ __forceinline__ float bfbits2f(unsigned int u) {
  union { unsigned int i; float f; } c; c.i = u << 16; return c.f;
}
__device__ __forceinline__ unsigned short f2bfbits(float f) {
  __hip_bfloat16 h = __float2bfloat16(f);
  return __builtin_bit_cast(unsigned short, h);
}

// async global->LDS, 16B per lane. LDS dest = wave-uniform base + lane*16.
__device__ __forceinline__ void g2l16(const void* g, void* l) {
  __builtin_amdgcn_global_load_lds((__attribute__((address_space(1))) void*)g,
                                   (__attribute__((address_space(3))) void*)l,
                                   16, 0, 0);
}

// fp32 -> bf16 conversion, 4 elems/thread (n % 4 == 0 for all our inputs)
__global__ __launch_bounds__(256)
void cvt_k(const float* __restrict__ in, __hip_bfloat16* __restrict__ out, int n)
{
  int i = (blockIdx.x * 256 + threadIdx.x) * 4;
  if (i >= n) return;
  float4 v = *(const float4*)(in + i);
  uint2 o;
  o.x = (unsigned)f2bfbits(v.x) | ((unsigned)f2bfbits(v.y) << 16);
  o.y = (unsigned)f2bfbits(v.z) | ((unsigned)f2bfbits(v.w) << 16);
  *(uint2*)(out + i) = o;
}

// ---------------------------------------------------------------------------
// GEMM: C[M,N] = A[M,K] @ B[N,K]^T + bias[N]  (+ optional ReLU, + optional
// residual R[M,N] added in epilogue). A,B bf16 (B dense [N,K]), bias fp32,
// C bf16 (OUTF32=0) or fp32 (OUTF32=1), fp32 accumulate. 128x128 tile,
// BK=32, 256 thr, 4 waves x (4x4) MFMA 16x16x32. Staging: global_load_lds
// width=16, single-buffer (r8 showed dbuf neutral-to-worse). LDS tile
// XOR-swizzled: logical 16B chunk (row,c) at physical chunk c ^ ((row>>1)&3)
// (r7: conflicts 6.3M -> 0). M%128==0, K%32==0; N edge via clamped loads +
// guarded stores.
// ---------------------------------------------------------------------------
template<int RELU, int OUTF32, int ADDRES>
__global__ __launch_bounds__(256, 2)
void gemm_bt(const __hip_bfloat16* __restrict__ A, int lda,
             const __hip_bfloat16* __restrict__ B,
             const float* __restrict__ bias,
             void* __restrict__ Cp, int ldc,
             const __hip_bfloat16* __restrict__ R, int ldr,
             int M, int N, int K)
{
  __shared__ __align__(16) __hip_bfloat16 As[128 * 32];
  __shared__ __align__(16) __hip_bfloat16 Bs[128 * 32];

  const int tid  = threadIdx.x;
  const int lane = tid & 63;
  const int wave = tid >> 6;
  const int quad = lane >> 4;
  const int l16  = lane & 15;
  const int m0 = blockIdx.y * 128;
  const int n0 = blockIdx.x * 128;
  const int wr = (wave >> 1) * 64;   // wave's 64x64 sub-tile
  const int wc = (wave & 1) * 64;

  // physical chunk p (16B LDS slot) = row*4 + pc; wave w's lanes fill slots
  // w*64+lane and w*64+256+lane. Source logical col8 = pc ^ ((row>>1)&3).
  const int p0  = wave * 64 + lane;
  const int p1  = p0 + 256;
  const int ar0 = p0 >> 2, ac0 = (((p0 & 3) ^ ((ar0 >> 1) & 3))) * 8;
  const int ar1 = p1 >> 2, ac1 = (((p1 & 3) ^ ((ar1 >> 1) & 3))) * 8;
  const int br0 = min(n0 + ar0, N - 1);   // clamp for N edge (loads valid
  const int br1 = min(n0 + ar1, N - 1);   // data; stores are guarded)
  __hip_bfloat16* lA0 = &As[(wave * 64)       * 8];
  __hip_bfloat16* lA1 = &As[(wave * 64 + 256) * 8];
  __hip_bfloat16* lB0 = &Bs[(wave * 64)       * 8];
  __hip_bfloat16* lB1 = &Bs[(wave * 64 + 256) * 8];

  f32x4 acc[4][4] = {};

  for (int k0 = 0; k0 < K; k0 += 32) {
    g2l16(A + (size_t)(m0 + ar0) * lda + k0 + ac0, lA0);
    g2l16(A + (size_t)(m0 + ar1) * lda + k0 + ac1, lA1);
    g2l16(B + (size_t)br0 * K + k0 + ac0, lB0);
    g2l16(B + (size_t)br1 * K + k0 + ac1, lB1);
    __syncthreads();   // drains vmcnt (global_load_lds) + barrier

    bf16x8 af[4], bfr[4];
#pragma unroll
    for (int i = 0; i < 4; i++) {  // A frag: lane holds A[m=row][k=quad*8..+7]
      const int row = wr + i * 16 + l16;
      af[i] = *(const bf16x8*)&As[row * 32 + ((quad ^ ((row >> 1) & 3)) * 8)];
    }
#pragma unroll
    for (int j = 0; j < 4; j++) {  // B frag: lane holds B[n=row][k=quad*8..+7]
      const int row = wc + j * 16 + l16;
      bfr[j] = *(const bf16x8*)&Bs[row * 32 + ((quad ^ ((row >> 1) & 3)) * 8)];
    }
#pragma unroll
    for (int i = 0; i < 4; i++)
#pragma unroll
      for (int j = 0; j < 4; j++)
        acc[i][j] = __builtin_amdgcn_mfma_f32_16x16x32_bf16(af[i], bfr[j], acc[i][j], 0, 0, 0);
    __syncthreads();   // all frag reads done before next tile's g2l writes
  }

  // epilogue: C/D layout col = lane&15, row = quad*4 + reg
#pragma unroll
  for (int j = 0; j < 4; j++) {
    int col = n0 + wc + j * 16 + l16;
    if (col < N) {
      float bv = bias[col];
#pragma unroll
      for (int i = 0; i < 4; i++) {
        int row = m0 + wr + i * 16 + quad * 4;
#pragma unroll
        for (int r = 0; r < 4; r++) {
          float v = acc[i][j][r] + bv;
          if (RELU) v = fmaxf(v, 0.f);
          if (ADDRES) v += __bfloat162float(R[(size_t)(row + r) * ldr + col]);
          if (OUTF32) ((float*)Cp)[(size_t)(row + r) * ldc + col] = v;
          else ((__hip_bfloat16*)Cp)[(size_t)(row + r) * ldc + col] = __float2bfloat16(v);
        }
      }
    }
  }
}

// ---------------------------------------------------------------------------
// Banded attention with LDS-staged K/V. One block per (b, h, 64-query chunk).
// Stages K and V rows [s0-4, s0+63] (68 rows x 256 dh, bf16) in LDS — each
// k/v row is read from HBM ONCE (previous kernel: 5x). 4 waves x 16 queries;
// per query the wave does 5 shuffle-reduced dots + softmax + weighted V sum.
// qkv rows [row=s*B+b][3H]: q@0, k@H, v@2H; ctx overwrites the q slot.
// ---------------------------------------------------------------------------
__global__ __launch_bounds__(256)
void attn_k(__hip_bfloat16* __restrict__ qkv)
{
  __shared__ __align__(16) __hip_bfloat16 Ks[68 * 256];
  __shared__ __align__(16) __hip_bfloat16 Vs[68 * 256];

  const int s0 = blockIdx.x * 64;
  const int b  = blockIdx.y >> 2;
  const int h  = blockIdx.y & 3;
  const int tid  = threadIdx.x;
  const int wave = tid >> 6;
  const int lane = tid & 63;
  const size_t hbase = (size_t)h * DHEAD;

  // stage: 68 rows x 32 chunks(16B) = 2176 chunks per matrix
  for (int c = tid; c < 68 * 32; c += 256) {
    const int row  = c >> 5;
    const int col8 = (c & 31) * 8;
    const int gs = s0 - 4 + row;
    if (gs >= 0) {
      const size_t gbase = (size_t)(gs * BATCH + b) * QKV_LD + hbase + col8;
      *(uint4*)&Ks[row * 256 + col8] = *(const uint4*)(qkv + gbase + H_DIM);
      *(uint4*)&Vs[row * 256 + col8] = *(const uint4*)(qkv + gbase + 2 * H_DIM);
    }
  }
  __syncthreads();

  for (int qi = 0; qi < 16; qi++) {
    const int s  = s0 + wave * 16 + qi;
    const int lr = wave * 16 + qi;              // LDS row of key j = s-4+jj is lr+jj
    const size_t qoff = (size_t)(s * BATCH + b) * QKV_LD + hbase + (lane << 2);

    float q0, q1, q2, q3;
    {
      uint2 t = *(const uint2*)(qkv + qoff);
      q0 = bfbits2f(t.x & 0xffff); q1 = bfbits2f(t.x >> 16);
      q2 = bfbits2f(t.y & 0xffff); q3 = bfbits2f(t.y >> 16);
    }

    float sc[WIN + 1];
#pragma unroll
    for (int jj = 0; jj <= WIN; jj++) {
      float v = -1e30f;
      if (s - WIN + jj >= 0) {
        uint2 t = *(const uint2*)&Ks[(lr + jj) * 256 + (lane << 2)];
        float p = q0 * bfbits2f(t.x & 0xffff) + q1 * bfbits2f(t.x >> 16)
                + q2 * bfbits2f(t.y & 0xffff) + q3 * bfbits2f(t.y >> 16);
#pragma unroll
        for (int o = 32; o; o >>= 1) p += __shfl_xor(p, o);
        v = p * 0.0625f;              // 1/sqrt(256)
      }
      sc[jj] = v;
    }

    float mx = sc[0];
#pragma unroll
    for (int jj = 1; jj <= WIN; jj++) mx = fmaxf(mx, sc[jj]);
    float p[WIN + 1], den = 0.f;
#pragma unroll
    for (int jj = 0; jj <= WIN; jj++) { p[jj] = __expf(sc[jj] - mx); den += p[jj]; }

    float a0 = 0.f, a1 = 0.f, a2 = 0.f, a3 = 0.f;
#pragma unroll
    for (int jj = 0; jj <= WIN; jj++) {
      if (s - WIN + jj >= 0) {
        uint2 t = *(const uint2*)&Vs[(lr + jj) * 256 + (lane << 2)];
        a0 += p[jj] * bfbits2f(t.x & 0xffff); a1 += p[jj] * bfbits2f(t.x >> 16);
        a2 += p[jj] * bfbits2f(t.y & 0xffff); a3 += p[jj] * bfbits2f(t.y >> 16);
      }
    }
    const float rl = 1.f / den;
    uint2 o;
    o.x = (unsigned)f2bfbits(a0 * rl) | ((unsigned)f2bfbits(a1 * rl) << 16);
    o.y = (unsigned)f2bfbits(a2 * rl) | ((unsigned)f2bfbits(a3 * rl) << 16);
    *(uint2*)(qkv + qoff) = o;        // ctx -> q slot
  }
}

// ---------------------------------------------------------------------------
// LayerNorm (single input stream — residual already added in GEMM epilogue).
// Reads y (stride ys), writes xout (stride H). One block per row, fp32 stats.
// ---------------------------------------------------------------------------
__global__ __launch_bounds__(256)
void ln_k(const __hip_bfloat16* __restrict__ y, int ys,
          const float* __restrict__ g, const float* __restrict__ be,
          __hip_bfloat16* __restrict__ xout)
{
  const int row = blockIdx.x, tid = threadIdx.x;
  uint2 yv = *(const uint2*)(y + (size_t)row * ys + tid * 4);
  float t0 = bfbits2f(yv.x & 0xffff);
  float t1 = bfbits2f(yv.x >> 16);
  float t2 = bfbits2f(yv.y & 0xffff);
  float t3 = bfbits2f(yv.y >> 16);
  float s  = t0 + t1 + t2 + t3;
  float ss = t0 * t0 + t1 * t1 + t2 * t2 + t3 * t3;
#pragma unroll
  for (int o = 32; o; o >>= 1) { s += __shfl_down(s, o); ss += __shfl_down(ss, o); }
  __shared__ float rs[4], rss[4];
  if ((tid & 63) == 0) { rs[tid >> 6] = s; rss[tid >> 6] = ss; }
  __syncthreads();
  float S  = rs[0] + rs[1] + rs[2] + rs[3];
  float SS = rss[0] + rss[1] + rss[2] + rss[3];
  const float inv = 1.f / (float)H_DIM;
  float mean = S * inv;
  float var  = SS * inv - mean * mean;       // biased var (jnp.var default)
  float rstd = rsqrtf(var + 1e-5f);
  float4 gv = *(const float4*)(g + tid * 4);
  float4 bv = *(const float4*)(be + tid * 4);
  float o0 = (t0 - mean) * rstd * gv.x + bv.x;
  float o1 = (t1 - mean) * rstd * gv.y + bv.y;
  float o2 = (t2 - mean) * rstd * gv.z + bv.z;
  float o3 = (t3 - mean) * rstd * gv.w + bv.w;
  uint2 ob;
  ob.x = (unsigned)f2bfbits(o0) | ((unsigned)f2bfbits(o1) << 16);
  ob.y = (unsigned)f2bfbits(o2) | ((unsigned)f2bfbits(o3) << 16);
  *(uint2*)(xout + (size_t)row * H_DIM + tid * 4) = ob;
}

// ---------------------------------------------------------------------------
extern "C" void kernel_launch(void* const* d_in, const int* in_sizes, int n_in,
                              void* d_out, int out_size, void* d_ws, size_t ws_size,
                              hipStream_t stream) {
  const float* src   = (const float*)d_in[0];
  const float* Wenc  = (const float*)d_in[1];
  const float* benc  = (const float*)d_in[2];
  const float* Wqkv  = (const float*)d_in[3];
  const float* bqkv  = (const float*)d_in[4];
  const float* Wo    = (const float*)d_in[5];
  const float* bo    = (const float*)d_in[6];
  const float* W1    = (const float*)d_in[7];
  const float* b1    = (const float*)d_in[8];
  const float* W2    = (const float*)d_in[9];
  const float* b2    = (const float*)d_in[10];
  const float* ln1s  = (const float*)d_in[11];
  const float* ln1b  = (const float*)d_in[12];
  const float* ln2s  = (const float*)d_in[13];
  const float* ln2b  = (const float*)d_in[14];
  const float* Wout  = (const float*)d_in[15];
  const float* bout  = (const float*)d_in[16];

  // ---- workspace (104 MiB total — footprint validated rounds 3/6) ----
  char* ws = (char*)d_ws;
  __hip_bfloat16* WB   = (__hip_bfloat16*)ws;      // bf16 arena (~37.3 MiB)
  __hip_bfloat16* srcb = WB;                       //   524288
  __hip_bfloat16* wenc = WB + 524288;              //    65536
  __hip_bfloat16* wqkv = WB + 589824;              //  9437184
  __hip_bfloat16* wo   = WB + 10027008;            //  3145728
  __hip_bfloat16* w1   = WB + 13172736;            //  3145728
  __hip_bfloat16* w2   = WB + 16318464;            //  3145728
  __hip_bfloat16* wout = WB + 19464192;            //    65536
  __hip_bfloat16* xb  = (__hip_bfloat16*)(ws + (size_t)40 * 1048576);  // 16 MiB
  __hip_bfloat16* qkv = (__hip_bfloat16*)(ws + (size_t)56 * 1048576);  // 48 MiB
  __hip_bfloat16* ctxp = qkv;             // q slot — attn output
  __hip_bfloat16* ybuf = qkv + H_DIM;     // k slot — (x + attn_out) / (x + ff)
  __hip_bfloat16* hbuf = qkv + 2 * H_DIM; // v slot — relu hidden temp

  const dim3 blk(256);
  #define CVT(inp, outp, n) cvt_k<<<dim3(((n) / 4 + 255) / 256), blk, 0, stream>>>(inp, outp, n)

  // ---- ingest: fp32 weights/src -> bf16 arenas (biases/LN stay fp32) ----
  CVT(src,  srcb, 524288);
  CVT(Wenc, wenc, 65536);
  CVT(Wqkv, wqkv, 9437184);
  CVT(Wo,   wo,   3145728);
  CVT(W1,   w1,   3145728);
  CVT(W2,   w2,   3145728);
  CVT(Wout, wout, 65536);

  // ---- encoder: x = src @ Wenc^T + benc   [8192,1024] ----
  gemm_bt<0, 0, 0><<<dim3(H_DIM / 128, ROWS / 128), blk, 0, stream>>>(
      srcb, IN_DIM, wenc, benc, xb, H_DIM, nullptr, 0, ROWS, H_DIM, IN_DIM);

  for (int l = 0; l < NLAYER; l++) {
    // qkv = x @ Wqkv^T + bqkv   [8192,3072]
    gemm_bt<0, 0, 0><<<dim3(QKV_LD / 128, ROWS / 128), blk, 0, stream>>>(
        xb, H_DIM, wqkv + (size_t)l * QKV_LD * H_DIM, bqkv + l * QKV_LD,
        qkv, QKV_LD, nullptr, 0, ROWS, QKV_LD, H_DIM);
    // banded attention (LDS-staged K/V); ctx -> q slot
    attn_k<<<dim3(S_LEN / 64, BATCH * NHEADS), blk, 0, stream>>>(qkv);
    // ybuf = x + ctx @ Wo^T + bo   (residual fused in epilogue)
    gemm_bt<0, 0, 1><<<dim3(H_DIM / 128, ROWS / 128), blk, 0, stream>>>(
        ctxp, QKV_LD, wo + (size_t)l * H_DIM * H_DIM, bo + l * H_DIM,
        ybuf, QKV_LD, xb, H_DIM, ROWS, H_DIM, H_DIM);
    // x = LN(ybuf)
    ln_k<<<dim3(ROWS), blk, 0, stream>>>(ybuf, QKV_LD, ln1s + l * H_DIM, ln1b + l * H_DIM, xb);
    // h = relu(x @ W1^T + b1) -> hbuf (v slot)
    gemm_bt<1, 0, 0><<<dim3(DFF_DIM / 128, ROWS / 128), blk, 0, stream>>>(
        xb, H_DIM, w1 + (size_t)l * DFF_DIM * H_DIM, b1 + l * DFF_DIM,
        hbuf, QKV_LD, nullptr, 0, ROWS, DFF_DIM, H_DIM);
    // ybuf = x + h @ W2^T + b2   (residual fused in epilogue)
    gemm_bt<0, 0, 1><<<dim3(H_DIM / 128, ROWS / 128), blk, 0, stream>>>(
        hbuf, QKV_LD, w2 + (size_t)l * H_DIM * DFF_DIM, b2 + l * H_DIM,
        ybuf, QKV_LD, xb, H_DIM, ROWS, H_DIM, DFF_DIM);
    // x = LN(ybuf)
    ln_k<<<dim3(ROWS), blk, 0, stream>>>(ybuf, QKV_LD, ln2s + l * H_DIM, ln2b + l * H_DIM, xb);
  }

  // ---- decoder: out = x @ Wout^T + bout   [8192,64] FP32 OUTPUT ----
  gemm_bt<0, 1, 0><<<dim3(1, ROWS / 128), blk, 0, stream>>>(
      xb, H_DIM, wout, bout, d_out, OUT_DIM, nullptr, 0, ROWS, OUT_DIM, H_DIM);
}

// Round 10
// 737.537 us; speedup vs baseline: 1.1630x; 1.1630x over previous
//
#include <hip/hip_runtime.h>
#include <hip/hip_bf16.h>

// Problem constants (from reference)
#define S_LEN   2048
#define BATCH   4
#define IN_DIM  64
#define H_DIM   1024
#define DFF_DIM 1024
#define OUT_DIM 64
#define NLAYER  3
#define NHEADS  4
#define DHEAD   256     // H / NHEAD
#define WIN     4       // banded window: j in [i-4, i]
#define ROWS    (S_LEN*BATCH)  // 8192 flattened (s,b) rows, row = s*B + b
#define QKV_LD  (3*H_DIM)      // 3072

// Established facts (rounds 0-9):
//  - inputs fp32, OUTPUT fp32; seq-major rows (row = s*B+b), window stride B.
//  - r7 = 797 us best. r8 dbuf neutral (m99/m100 replicated). r9 LDS-staged
//    attention REGRESSED (+60 us: 16-query serial loop per wave killed
//    parallelism; L2 already absorbed the 5x k/v re-read). GEMM binder is
//    the per-barrier vmcnt(0) drain over only 16 MFMAs.
// This round: BK=64 GEMM (32 MFMA per barrier, 32 KB LDS, row&7 XOR swizzle);
// attention reverted to r7 wave-per-query; residual fusion + ln_k kept.

typedef __bf16 bf16x8 __attribute__((ext_vector_type(8)));
typedef float  f32x4  __attribute__((ext_vector_type(4)));

__device__ __forceinline__ float bfbits2f(unsigned int u) {
  union { unsigned int i; float f; } c; c.i = u << 16; return c.f;
}
__device__ __forceinline__ unsigned short f2bfbits(float f) {
  __hip_bfloat16 h = __float2bfloat16(f);
  return __builtin_bit_cast(unsigned short, h);
}

// async global->LDS, 16B per lane. LDS dest = wave-uniform base + lane*16.
__device__ __forceinline__ void g2l16(const void* g, void* l) {
  __builtin_amdgcn_global_load_lds((__attribute__((address_space(1))) void*)g,
                                   (__attribute__((address_space(3))) void*)l,
                                   16, 0, 0);
}

// fp32 -> bf16 conversion, 4 elems/thread (n % 4 == 0 for all our inputs)
__global__ __launch_bounds__(256)
void cvt_k(const float* __restrict__ in, __hip_bfloat16* __restrict__ out, int n)
{
  int i = (blockIdx.x * 256 + threadIdx.x) * 4;
  if (i >= n) return;
  float4 v = *(const float4*)(in + i);
  uint2 o;
  o.x = (unsigned)f2bfbits(v.x) | ((unsigned)f2bfbits(v.y) << 16);
  o.y = (unsigned)f2bfbits(v.z) | ((unsigned)f2bfbits(v.w) << 16);
  *(uint2*)(out + i) = o;
}

// ---------------------------------------------------------------------------
// GEMM: C[M,N] = A[M,K] @ B[N,K]^T + bias[N]  (+ optional ReLU, + optional
// residual R[M,N]). A,B bf16 (B dense [N,K]), bias fp32, C bf16/fp32, fp32
// accumulate. 128x128 tile, BK=64 (2 K-halves, 32 MFMA per barrier — r7-r9
// showed 16 MFMAs/barrier leaves the vmcnt(0) drain exposed; AITER runs ~32),
// 256 thr, 4 waves x (4x4) MFMA 16x16x32. LDS 2x16KB, XOR swizzle for the
// 8-chunk rows: physical chunk pc = c ^ (row&7) => every 8-lane issue group
// covers all 32 banks (read and staged-write sides both conflict-free).
// M%128==0, K%64==0 required (all our K: 64/1024); N edge via clamped loads
// + guarded stores.
// ---------------------------------------------------------------------------
template<int RELU, int OUTF32, int ADDRES>
__global__ __launch_bounds__(256, 2)
void gemm_bt(const __hip_bfloat16* __restrict__ A, int lda,
             const __hip_bfloat16* __restrict__ B,
             const float* __restrict__ bias,
             void* __restrict__ Cp, int ldc,
             const __hip_bfloat16* __restrict__ R, int ldr,
             int M, int N, int K)
{
  __shared__ __align__(16) __hip_bfloat16 As[128 * 64];
  __shared__ __align__(16) __hip_bfloat16 Bs[128 * 64];

  const int tid  = threadIdx.x;
  const int lane = tid & 63;
  const int wave = tid >> 6;
  const int quad = lane >> 4;
  const int l16  = lane & 15;
  const int m0 = blockIdx.y * 128;
  const int n0 = blockIdx.x * 128;
  const int wr = (wave >> 1) * 64;   // wave's 64x64 sub-tile
  const int wc = (wave & 1) * 64;

  // staging: tile = 128 rows x 8 chunks(16B) = 1024 chunks per matrix.
  // thread handles physical chunks p = tid + 256*set, set=0..3; LDS dest is
  // wave-uniform base (wave*64 + set*256)*16 + lane*16. Source logical col8
  // = (p&7) ^ ((p>>3)&7)  (the XOR swizzle, inverted on the write side).
  int arow[4], acol[4], brow[4];
#pragma unroll
  for (int s = 0; s < 4; s++) {
    const int p = tid + (s << 8);
    arow[s] = p >> 3;
    acol[s] = ((p & 7) ^ ((p >> 3) & 7)) * 8;
    brow[s] = min(n0 + arow[s], N - 1);   // clamp for N edge
  }

  f32x4 acc[4][4] = {};
  const int nk = K >> 6;

  for (int t = 0; t < nk; ++t) {
    const int k0 = t << 6;
#pragma unroll
    for (int s = 0; s < 4; s++) {
      const int lo = (wave * 64 + (s << 8)) * 8;   // chunk*8 elems
      g2l16(A + (size_t)(m0 + arow[s]) * lda + k0 + acol[s], &As[lo]);
      g2l16(B + (size_t)brow[s] * K + k0 + acol[s], &Bs[lo]);
    }
    __syncthreads();   // drains vmcnt (global_load_lds) + barrier

#pragma unroll
    for (int kh = 0; kh < 2; kh++) {
      bf16x8 af[4], bfr[4];
#pragma unroll
      for (int i = 0; i < 4; i++) {  // A frag: lane holds A[m=row][k=kh*32+quad*8..+7]
        const int row = wr + i * 16 + l16;
        const int c   = (kh * 4 + quad) ^ (row & 7);
        af[i] = *(const bf16x8*)&As[row * 64 + c * 8];
      }
#pragma unroll
      for (int j = 0; j < 4; j++) {  // B frag
        const int row = wc + j * 16 + l16;
        const int c   = (kh * 4 + quad) ^ (row & 7);
        bfr[j] = *(const bf16x8*)&Bs[row * 64 + c * 8];
      }
#pragma unroll
      for (int i = 0; i < 4; i++)
#pragma unroll
        for (int j = 0; j < 4; j++)
          acc[i][j] = __builtin_amdgcn_mfma_f32_16x16x32_bf16(af[i], bfr[j], acc[i][j], 0, 0, 0);
    }
    __syncthreads();   // all frag reads done before next tile's g2l writes
  }

  // epilogue: C/D layout col = lane&15, row = quad*4 + reg
#pragma unroll
  for (int j = 0; j < 4; j++) {
    int col = n0 + wc + j * 16 + l16;
    if (col < N) {
      float bv = bias[col];
#pragma unroll
      for (int i = 0; i < 4; i++) {
        int row = m0 + wr + i * 16 + quad * 4;
#pragma unroll
        for (int r = 0; r < 4; r++) {
          float v = acc[i][j][r] + bv;
          if (RELU) v = fmaxf(v, 0.f);
          if (ADDRES) v += __bfloat162float(R[(size_t)(row + r) * ldr + col]);
          if (OUTF32) ((float*)Cp)[(size_t)(row + r) * ldc + col] = v;
          else ((__hip_bfloat16*)Cp)[(size_t)(row + r) * ldc + col] = __float2bfloat16(v);
        }
      }
    }
  }
}

// ---------------------------------------------------------------------------
// Banded attention (r7 version — one wave per (s,b,h), fully parallel; r9's
// LDS-staged variant regressed by serializing 16 queries per wave).
// Window = 5 keys (j in [s-4, s]). dh=256 => 4 elems/lane. qkv rows [3H]:
// q@0, k@H, v@2H; head h at h*256. ctx overwrites the q slot.
// ---------------------------------------------------------------------------
__global__ __launch_bounds__(256)
void attn_k(__hip_bfloat16* __restrict__ qkv)
{
  const int gw   = (blockIdx.x << 2) + (threadIdx.x >> 6);
  const int lane = threadIdx.x & 63;
  const int h = gw & (NHEADS - 1);
  const int b = (gw >> 2) & (BATCH - 1);
  const int s = gw >> 4;
  const size_t hoff = (size_t)h * DHEAD + (lane << 2);

  float q0, q1, q2, q3;
  {
    uint2 t = *(const uint2*)(qkv + (size_t)(s * BATCH + b) * QKV_LD + hoff);
    q0 = bfbits2f(t.x & 0xffff); q1 = bfbits2f(t.x >> 16);
    q2 = bfbits2f(t.y & 0xffff); q3 = bfbits2f(t.y >> 16);
  }

  float sc[WIN + 1];
#pragma unroll
  for (int jj = 0; jj <= WIN; jj++) {
    int j = s - WIN + jj;           // wave-uniform
    float v = -1e30f;
    if (j >= 0) {
      uint2 t = *(const uint2*)(qkv + (size_t)(j * BATCH + b) * QKV_LD + H_DIM + hoff);
      float p = q0 * bfbits2f(t.x & 0xffff) + q1 * bfbits2f(t.x >> 16)
              + q2 * bfbits2f(t.y & 0xffff) + q3 * bfbits2f(t.y >> 16);
#pragma unroll
      for (int o = 32; o; o >>= 1) p += __shfl_xor(p, o);
      v = p * 0.0625f;              // 1/sqrt(256)
    }
    sc[jj] = v;
  }

  float mx = sc[0];
#pragma unroll
  for (int jj = 1; jj <= WIN; jj++) mx = fmaxf(mx, sc[jj]);
  float p[WIN + 1], den = 0.f;
#pragma unroll
  for (int jj = 0; jj <= WIN; jj++) { p[jj] = __expf(sc[jj] - mx); den += p[jj]; }

  float a0 = 0.f, a1 = 0.f, a2 = 0.f, a3 = 0.f;
#pragma unroll
  for (int jj = 0; jj <= WIN; jj++) {
    int j = s - WIN + jj;
    if (j >= 0) {
      uint2 t = *(const uint2*)(qkv + (size_t)(j * BATCH + b) * QKV_LD + 2 * H_DIM + hoff);
      a0 += p[jj] * bfbits2f(t.x & 0xffff); a1 += p[jj] * bfbits2f(t.x >> 16);
      a2 += p[jj] * bfbits2f(t.y & 0xffff); a3 += p[jj] * bfbits2f(t.y >> 16);
    }
  }
  float rl = 1.f / den;
  uint2 o;
  o.x = (unsigned)f2bfbits(a0 * rl) | ((unsigned)f2bfbits(a1 * rl) << 16);
  o.y = (unsigned)f2bfbits(a2 * rl) | ((unsigned)f2bfbits(a3 * rl) << 16);
  *(uint2*)(qkv + (size_t)(s * BATCH + b) * QKV_LD + hoff) = o;  // ctx -> q slot
}

// ---------------------------------------------------------------------------
// LayerNorm (single input stream — residual already added in GEMM epilogue).
// Reads y (stride ys), writes xout (stride H). One block per row, fp32 stats.
// ---------------------------------------------------------------------------
__global__ __launch_bounds__(256)
void ln_k(const __hip_bfloat16* __restrict__ y, int ys,
          const float* __restrict__ g, const float* __restrict__ be,
          __hip_bfloat16* __restrict__ xout)
{
  const int row = blockIdx.x, tid = threadIdx.x;
  uint2 yv = *(const uint2*)(y + (size_t)row * ys + tid * 4);
  float t0 = bfbits2f(yv.x & 0xffff);
  float t1 = bfbits2f(yv.x >> 16);
  float t2 = bfbits2f(yv.y & 0xffff);
  float t3 = bfbits2f(yv.y >> 16);
  float s  = t0 + t1 + t2 + t3;
  float ss = t0 * t0 + t1 * t1 + t2 * t2 + t3 * t3;
#pragma unroll
  for (int o = 32; o; o >>= 1) { s += __shfl_down(s, o); ss += __shfl_down(ss, o); }
  __shared__ float rs[4], rss[4];
  if ((tid & 63) == 0) { rs[tid >> 6] = s; rss[tid >> 6] = ss; }
  __syncthreads();
  float S  = rs[0] + rs[1] + rs[2] + rs[3];
  float SS = rss[0] + rss[1] + rss[2] + rss[3];
  const float inv = 1.f / (float)H_DIM;
  float mean = S * inv;
  float var  = SS * inv - mean * mean;       // biased var (jnp.var default)
  float rstd = rsqrtf(var + 1e-5f);
  float4 gv = *(const float4*)(g + tid * 4);
  float4 bv = *(const float4*)(be + tid * 4);
  float o0 = (t0 - mean) * rstd * gv.x + bv.x;
  float o1 = (t1 - mean) * rstd * gv.y + bv.y;
  float o2 = (t2 - mean) * rstd * gv.z + bv.z;
  float o3 = (t3 - mean) * rstd * gv.w + bv.w;
  uint2 ob;
  ob.x = (unsigned)f2bfbits(o0) | ((unsigned)f2bfbits(o1) << 16);
  ob.y = (unsigned)f2bfbits(o2) | ((unsigned)f2bfbits(o3) << 16);
  *(uint2*)(xout + (size_t)row * H_DIM + tid * 4) = ob;
}

// ---------------------------------------------------------------------------
extern "C" void kernel_launch(void* const* d_in, const int* in_sizes, int n_in,
                              void* d_out, int out_size, void* d_ws, size_t ws_size,
                              hipStream_t stream) {
  const float* src   = (const float*)d_in[0];
  const float* Wenc  = (const float*)d_in[1];
  const float* benc  = (const float*)d_in[2];
  const float* Wqkv  = (const float*)d_in[3];
  const float* bqkv  = (const float*)d_in[4];
  const float* Wo    = (const float*)d_in[5];
  const float* bo    = (const float*)d_in[6];
  const float* W1    = (const float*)d_in[7];
  const float* b1    = (const float*)d_in[8];
  const float* W2    = (const float*)d_in[9];
  const float* b2    = (const float*)d_in[10];
  const float* ln1s  = (const float*)d_in[11];
  const float* ln1b  = (const float*)d_in[12];
  const float* ln2s  = (const float*)d_in[13];
  const float* ln2b  = (const float*)d_in[14];
  const float* Wout  = (const float*)d_in[15];
  const float* bout  = (const float*)d_in[16];

  // ---- workspace (104 MiB total — footprint validated rounds 3/6) ----
  char* ws = (char*)d_ws;
  __hip_bfloat16* WB   = (__hip_bfloat16*)ws;      // bf16 arena (~37.3 MiB)
  __hip_bfloat16* srcb = WB;                       //   524288
  __hip_bfloat16* wenc = WB + 524288;              //    65536
  __hip_bfloat16* wqkv = WB + 589824;              //  9437184
  __hip_bfloat16* wo   = WB + 10027008;            //  3145728
  __hip_bfloat16* w1   = WB + 13172736;            //  3145728
  __hip_bfloat16* w2   = WB + 16318464;            //  3145728
  __hip_bfloat16* wout = WB + 19464192;            //    65536
  __hip_bfloat16* xb  = (__hip_bfloat16*)(ws + (size_t)40 * 1048576);  // 16 MiB
  __hip_bfloat16* qkv = (__hip_bfloat16*)(ws + (size_t)56 * 1048576);  // 48 MiB
  __hip_bfloat16* ctxp = qkv;             // q slot — attn output
  __hip_bfloat16* ybuf = qkv + H_DIM;     // k slot — (x + attn_out) / (x + ff)
  __hip_bfloat16* hbuf = qkv + 2 * H_DIM; // v slot — relu hidden temp

  const dim3 blk(256);
  #define CVT(inp, outp, n) cvt_k<<<dim3(((n) / 4 + 255) / 256), blk, 0, stream>>>(inp, outp, n)

  // ---- ingest: fp32 weights/src -> bf16 arenas (biases/LN stay fp32) ----
  CVT(src,  srcb, 524288);
  CVT(Wenc, wenc, 65536);
  CVT(Wqkv, wqkv, 9437184);
  CVT(Wo,   wo,   3145728);
  CVT(W1,   w1,   3145728);
  CVT(W2,   w2,   3145728);
  CVT(Wout, wout, 65536);

  // ---- encoder: x = src @ Wenc^T + benc   [8192,1024] (K=64 -> 1 tile) ----
  gemm_bt<0, 0, 0><<<dim3(H_DIM / 128, ROWS / 128), blk, 0, stream>>>(
      srcb, IN_DIM, wenc, benc, xb, H_DIM, nullptr, 0, ROWS, H_DIM, IN_DIM);

  for (int l = 0; l < NLAYER; l++) {
    // qkv = x @ Wqkv^T + bqkv   [8192,3072]
    gemm_bt<0, 0, 0><<<dim3(QKV_LD / 128, ROWS / 128), blk, 0, stream>>>(
        xb, H_DIM, wqkv + (size_t)l * QKV_LD * H_DIM, bqkv + l * QKV_LD,
        qkv, QKV_LD, nullptr, 0, ROWS, QKV_LD, H_DIM);
    // banded attention; ctx -> q slot
    attn_k<<<dim3(ROWS * NHEADS / 4), blk, 0, stream>>>(qkv);
    // ybuf = x + ctx @ Wo^T + bo   (residual fused in epilogue)
    gemm_bt<0, 0, 1><<<dim3(H_DIM / 128, ROWS / 128), blk, 0, stream>>>(
        ctxp, QKV_LD, wo + (size_t)l * H_DIM * H_DIM, bo + l * H_DIM,
        ybuf, QKV_LD, xb, H_DIM, ROWS, H_DIM, H_DIM);
    // x = LN(ybuf)
    ln_k<<<dim3(ROWS), blk, 0, stream>>>(ybuf, QKV_LD, ln1s + l * H_DIM, ln1b + l * H_DIM, xb);
    // h = relu(x @ W1^T + b1) -> hbuf (v slot)
    gemm_bt<1, 0, 0><<<dim3(DFF_DIM / 128, ROWS / 128), blk, 0, stream>>>(
        xb, H_DIM, w1 + (size_t)l * DFF_DIM * H_DIM, b1 + l * DFF_DIM,
        hbuf, QKV_LD, nullptr, 0, ROWS, DFF_DIM, H_DIM);
    // ybuf = x + h @ W2^T + b2   (residual fused in epilogue)
    gemm_bt<0, 0, 1><<<dim3(H_DIM / 128, ROWS / 128), blk, 0, stream>>>(
        hbuf, QKV_LD, w2 + (size_t)l * H_DIM * DFF_DIM, b2 + l * H_DIM,
        ybuf, QKV_LD, xb, H_DIM, ROWS, H_DIM, DFF_DIM);
    // x = LN(ybuf)
    ln_k<<<dim3(ROWS), blk, 0, stream>>>(ybuf, QKV_LD, ln2s + l * H_DIM, ln2b + l * H_DIM, xb);
  }

  // ---- decoder: out = x @ Wout^T + bout   [8192,64] FP32 OUTPUT ----
  gemm_bt<0, 1, 0><<<dim3(1, ROWS / 128), blk, 0, stream>>>(
      xb, H_DIM, wout, bout, d_out, OUT_DIM, nullptr, 0, ROWS, OUT_DIM, H_DIM);
}

// Round 11
// 728.491 us; speedup vs baseline: 1.1774x; 1.0124x over previous
//
#include <hip/hip_runtime.h>
#include <hip/hip_bf16.h>

// Problem constants (from reference)
#define S_LEN   2048
#define BATCH   4
#define IN_DIM  64
#define H_DIM   1024
#define DFF_DIM 1024
#define OUT_DIM 64
#define NLAYER  3
#define NHEADS  4
#define DHEAD   256     // H / NHEAD
#define WIN     4       // banded window: j in [i-4, i]
#define ROWS    (S_LEN*BATCH)  // 8192 flattened (s,b) rows, row = s*B + b
#define QKV_LD  (3*H_DIM)      // 3072

// Established facts (rounds 0-10):
//  - inputs fp32, OUTPUT fp32; seq-major rows (row = s*B+b), window stride B.
//  - r10 = 737.5 us. BK=64 (32 MFMA/barrier) WIN: QKV 78->58.6 us, MfmaUtil
//    37%, conflicts 0 => 879 TF = the m97-family structural plateau. In-GEMM
//    K-loop tuning is exhausted (r8 dbuf neutral, m132 BK=128 regresses).
//  - QKV FETCH 73MB vs 22 ideal: per-XCD B re-fetch (x-fastest dispatch).
// This round: (1) supertile block swizzle (4 m-tiles, n-fast) for L2 reuse;
// (2) wave-per-row LN (shuffle-only); (3) merged cvt kernel.

typedef __bf16 bf16x8 __attribute__((ext_vector_type(8)));
typedef float  f32x4  __attribute__((ext_vector_type(4)));

__device__ __forceinline__ float bfbits2f(unsigned int u) {
  union { unsigned int i; float f; } c; c.i = u << 16; return c.f;
}
__device__ __forceinline__ unsigned short f2bfbits(float f) {
  __hip_bfloat16 h = __float2bfloat16(f);
  return __builtin_bit_cast(unsigned short, h);
}

// async global->LDS, 16B per lane. LDS dest = wave-uniform base + lane*16.
__device__ __forceinline__ void g2l16(const void* g, void* l) {
  __builtin_amdgcn_global_load_lds((__attribute__((address_space(1))) void*)g,
                                   (__attribute__((address_space(3))) void*)l,
                                   16, 0, 0);
}

// ---------------------------------------------------------------------------
// Merged fp32->bf16 ingest: all 7 weight/src segments in ONE dispatch.
// Segment boundaries are compile-time constants; thread finds its segment by
// comparing against cumulative offsets (trivial VALU, memory-bound kernel).
// ---------------------------------------------------------------------------
struct CvtSeg { const float* src; __hip_bfloat16* dst; int n4; };  // n4 = n/4

__global__ __launch_bounds__(256)
void cvt_all_k(CvtSeg s0, CvtSeg s1, CvtSeg s2, CvtSeg s3,
               CvtSeg s4, CvtSeg s5, CvtSeg s6)
{
  int i = blockIdx.x * 256 + threadIdx.x;   // index in unit of 4 elems
  CvtSeg seg;
  if      (i < s0.n4) { seg = s0; }
  else if ((i -= s0.n4) < s1.n4) { seg = s1; }
  else if ((i -= s1.n4) < s2.n4) { seg = s2; }
  else if ((i -= s2.n4) < s3.n4) { seg = s3; }
  else if ((i -= s3.n4) < s4.n4) { seg = s4; }
  else if ((i -= s4.n4) < s5.n4) { seg = s5; }
  else if ((i -= s5.n4) < s6.n4) { seg = s6; }
  else return;
  float4 v = *(const float4*)(seg.src + (size_t)i * 4);
  uint2 o;
  o.x = (unsigned)f2bfbits(v.x) | ((unsigned)f2bfbits(v.y) << 16);
  o.y = (unsigned)f2bfbits(v.z) | ((unsigned)f2bfbits(v.w) << 16);
  *(uint2*)(seg.dst + (size_t)i * 4) = o;
}

// ---------------------------------------------------------------------------
// GEMM: C[M,N] = A[M,K] @ B[N,K]^T + bias[N]  (+ optional ReLU, + optional
// residual R[M,N]). A,B bf16 (B dense [N,K]), bias fp32, C bf16/fp32, fp32
// accumulate. 128x128 tile, BK=64 (32 MFMA/barrier — r10 WIN), 256 thr,
// 4 waves x (4x4) MFMA 16x16x32. LDS 2x16KB, XOR swizzle pc = c ^ (row&7)
// (conflict-free both sides, r7/r10: SQ_LDS_BANK_CONFLICT = 0).
// Block swizzle: linear id -> supertile of 4 m-tiles with n fastest, so the
// ~8 consecutive blocks that land round-robin on the 8 XCDs share a 1MB
// A-stripe and a small B window; per-XCD B working set ~N/2 tiles stays L2-
// resident across groups (r10 FETCH showed 8x B re-fetch). gy%4==0 required
// (all our GEMMs: gy=64). M%128==0, K%64==0; N edge clamped+guarded.
// ---------------------------------------------------------------------------
template<int RELU, int OUTF32, int ADDRES>
__global__ __launch_bounds__(256, 2)
void gemm_bt(const __hip_bfloat16* __restrict__ A, int lda,
             const __hip_bfloat16* __restrict__ B,
             const float* __restrict__ bias,
             void* __restrict__ Cp, int ldc,
             const __hip_bfloat16* __restrict__ R, int ldr,
             int M, int N, int K)
{
  __shared__ __align__(16) __hip_bfloat16 As[128 * 64];
  __shared__ __align__(16) __hip_bfloat16 Bs[128 * 64];

  const int tid  = threadIdx.x;
  const int lane = tid & 63;
  const int wave = tid >> 6;
  const int quad = lane >> 4;
  const int l16  = lane & 15;

  // supertile remap: lin -> (mt, nt); 4 m-tiles per group, n fastest.
  const int gx  = gridDim.x;
  const int lin = blockIdx.y * gx + blockIdx.x;
  const int gsz = 4 * gx;
  const int mt  = (lin / gsz) * 4 + (lin & 3);
  const int nt  = (lin % gsz) >> 2;
  const int m0 = mt * 128;
  const int n0 = nt * 128;

  const int wr = (wave >> 1) * 64;   // wave's 64x64 sub-tile
  const int wc = (wave & 1) * 64;

  // staging: tile = 128 rows x 8 chunks(16B) = 1024 chunks per matrix.
  // thread handles physical chunks p = tid + 256*set; source logical col8
  // = (p&7) ^ ((p>>3)&7)  (XOR swizzle inverted on the write side).
  int arow[4], acol[4], brow[4];
#pragma unroll
  for (int s = 0; s < 4; s++) {
    const int p = tid + (s << 8);
    arow[s] = p >> 3;
    acol[s] = ((p & 7) ^ ((p >> 3) & 7)) * 8;
    brow[s] = min(n0 + arow[s], N - 1);   // clamp for N edge
  }

  f32x4 acc[4][4] = {};
  const int nk = K >> 6;

  for (int t = 0; t < nk; ++t) {
    const int k0 = t << 6;
#pragma unroll
    for (int s = 0; s < 4; s++) {
      const int lo = (wave * 64 + (s << 8)) * 8;   // chunk*8 elems
      g2l16(A + (size_t)(m0 + arow[s]) * lda + k0 + acol[s], &As[lo]);
      g2l16(B + (size_t)brow[s] * K + k0 + acol[s], &Bs[lo]);
    }
    __syncthreads();   // drains vmcnt (global_load_lds) + barrier

#pragma unroll
    for (int kh = 0; kh < 2; kh++) {
      bf16x8 af[4], bfr[4];
#pragma unroll
      for (int i = 0; i < 4; i++) {  // A frag: lane holds A[m=row][k=kh*32+quad*8..+7]
        const int row = wr + i * 16 + l16;
        const int c   = (kh * 4 + quad) ^ (row & 7);
        af[i] = *(const bf16x8*)&As[row * 64 + c * 8];
      }
#pragma unroll
      for (int j = 0; j < 4; j++) {  // B frag
        const int row = wc + j * 16 + l16;
        const int c   = (kh * 4 + quad) ^ (row & 7);
        bfr[j] = *(const bf16x8*)&Bs[row * 64 + c * 8];
      }
#pragma unroll
      for (int i = 0; i < 4; i++)
#pragma unroll
        for (int j = 0; j < 4; j++)
          acc[i][j] = __builtin_amdgcn_mfma_f32_16x16x32_bf16(af[i], bfr[j], acc[i][j], 0, 0, 0);
    }
    __syncthreads();   // all frag reads done before next tile's g2l writes
  }

  // epilogue: C/D layout col = lane&15, row = quad*4 + reg
#pragma unroll
  for (int j = 0; j < 4; j++) {
    int col = n0 + wc + j * 16 + l16;
    if (col < N) {
      float bv = bias[col];
#pragma unroll
      for (int i = 0; i < 4; i++) {
        int row = m0 + wr + i * 16 + quad * 4;
#pragma unroll
        for (int r = 0; r < 4; r++) {
          float v = acc[i][j][r] + bv;
          if (RELU) v = fmaxf(v, 0.f);
          if (ADDRES) v += __bfloat162float(R[(size_t)(row + r) * ldr + col]);
          if (OUTF32) ((float*)Cp)[(size_t)(row + r) * ldc + col] = v;
          else ((__hip_bfloat16*)Cp)[(size_t)(row + r) * ldc + col] = __float2bfloat16(v);
        }
      }
    }
  }
}

// ---------------------------------------------------------------------------
// Banded attention (r7 winner — one wave per (s,b,h), fully parallel).
// Window = 5 keys (j in [s-4, s]). dh=256 => 4 elems/lane. qkv rows [3H]:
// q@0, k@H, v@2H; head h at h*256. ctx overwrites the q slot.
// ---------------------------------------------------------------------------
__global__ __launch_bounds__(256)
void attn_k(__hip_bfloat16* __restrict__ qkv)
{
  const int gw   = (blockIdx.x << 2) + (threadIdx.x >> 6);
  const int lane = threadIdx.x & 63;
  const int h = gw & (NHEADS - 1);
  const int b = (gw >> 2) & (BATCH - 1);
  const int s = gw >> 4;
  const size_t hoff = (size_t)h * DHEAD + (lane << 2);

  float q0, q1, q2, q3;
  {
    uint2 t = *(const uint2*)(qkv + (size_t)(s * BATCH + b) * QKV_LD + hoff);
    q0 = bfbits2f(t.x & 0xffff); q1 = bfbits2f(t.x >> 16);
    q2 = bfbits2f(t.y & 0xffff); q3 = bfbits2f(t.y >> 16);
  }

  float sc[WIN + 1];
#pragma unroll
  for (int jj = 0; jj <= WIN; jj++) {
    int j = s - WIN + jj;           // wave-uniform
    float v = -1e30f;
    if (j >= 0) {
      uint2 t = *(const uint2*)(qkv + (size_t)(j * BATCH + b) * QKV_LD + H_DIM + hoff);
      float p = q0 * bfbits2f(t.x & 0xffff) + q1 * bfbits2f(t.x >> 16)
              + q2 * bfbits2f(t.y & 0xffff) + q3 * bfbits2f(t.y >> 16);
#pragma unroll
      for (int o = 32; o; o >>= 1) p += __shfl_xor(p, o);
      v = p * 0.0625f;              // 1/sqrt(256)
    }
    sc[jj] = v;
  }

  float mx = sc[0];
#pragma unroll
  for (int jj = 1; jj <= WIN; jj++) mx = fmaxf(mx, sc[jj]);
  float p[WIN + 1], den = 0.f;
#pragma unroll
  for (int jj = 0; jj <= WIN; jj++) { p[jj] = __expf(sc[jj] - mx); den += p[jj]; }

  float a0 = 0.f, a1 = 0.f, a2 = 0.f, a3 = 0.f;
#pragma unroll
  for (int jj = 0; jj <= WIN; jj++) {
    int j = s - WIN + jj;
    if (j >= 0) {
      uint2 t = *(const uint2*)(qkv + (size_t)(j * BATCH + b) * QKV_LD + 2 * H_DIM + hoff);
      a0 += p[jj] * bfbits2f(t.x & 0xffff); a1 += p[jj] * bfbits2f(t.x >> 16);
      a2 += p[jj] * bfbits2f(t.y & 0xffff); a3 += p[jj] * bfbits2f(t.y >> 16);
    }
  }
  float rl = 1.f / den;
  uint2 o;
  o.x = (unsigned)f2bfbits(a0 * rl) | ((unsigned)f2bfbits(a1 * rl) << 16);
  o.y = (unsigned)f2bfbits(a2 * rl) | ((unsigned)f2bfbits(a3 * rl) << 16);
  *(uint2*)(qkv + (size_t)(s * BATCH + b) * QKV_LD + hoff) = o;  // ctx -> q slot
}

// ---------------------------------------------------------------------------
// LayerNorm, ONE WAVE PER ROW (shuffle-only, no __syncthreads; r9's LDS-tree
// version cost a barrier + LDS round-trip). 4 rows per 256-thr block; each
// lane holds 16 elems (2 x uint4). Residual already added in GEMM epilogue.
// ---------------------------------------------------------------------------
__global__ __launch_bounds__(256)
void ln_k(const __hip_bfloat16* __restrict__ y, int ys,
          const float* __restrict__ g, const float* __restrict__ be,
          __hip_bfloat16* __restrict__ xout)
{
  const int row  = blockIdx.x * 4 + (threadIdx.x >> 6);
  const int lane = threadIdx.x & 63;
  const int e0   = lane * 16;
  const __hip_bfloat16* yp = y + (size_t)row * ys + e0;

  uint2 v[4];
  *(uint4*)&v[0] = *(const uint4*)yp;
  *(uint4*)&v[2] = *(const uint4*)(yp + 8);
  float t[16];
#pragma unroll
  for (int k = 0; k < 4; k++) {
    t[k * 4 + 0] = bfbits2f(v[k].x & 0xffff);
    t[k * 4 + 1] = bfbits2f(v[k].x >> 16);
    t[k * 4 + 2] = bfbits2f(v[k].y & 0xffff);
    t[k * 4 + 3] = bfbits2f(v[k].y >> 16);
  }
  float s = 0.f, ss = 0.f;
#pragma unroll
  for (int k = 0; k < 16; k++) { s += t[k]; ss += t[k] * t[k]; }
#pragma unroll
  for (int o = 32; o; o >>= 1) { s += __shfl_xor(s, o); ss += __shfl_xor(ss, o); }

  const float inv  = 1.f / (float)H_DIM;
  const float mean = s * inv;
  const float var  = ss * inv - mean * mean;   // biased var (jnp.var default)
  const float rstd = rsqrtf(var + 1e-5f);

  float4 gv[4], bv[4];
#pragma unroll
  for (int k = 0; k < 4; k++) {
    gv[k] = *(const float4*)(g + e0 + k * 4);
    bv[k] = *(const float4*)(be + e0 + k * 4);
  }
  uint2 ob[4];
#pragma unroll
  for (int k = 0; k < 4; k++) {
    float o0 = (t[k*4+0] - mean) * rstd * gv[k].x + bv[k].x;
    float o1 = (t[k*4+1] - mean) * rstd * gv[k].y + bv[k].y;
    float o2 = (t[k*4+2] - mean) * rstd * gv[k].z + bv[k].z;
    float o3 = (t[k*4+3] - mean) * rstd * gv[k].w + bv[k].w;
    ob[k].x = (unsigned)f2bfbits(o0) | ((unsigned)f2bfbits(o1) << 16);
    ob[k].y = (unsigned)f2bfbits(o2) | ((unsigned)f2bfbits(o3) << 16);
  }
  __hip_bfloat16* xp = xout + (size_t)row * H_DIM + e0;
  *(uint4*)xp       = *(const uint4*)&ob[0];
  *(uint4*)(xp + 8) = *(const uint4*)&ob[2];
}

// ---------------------------------------------------------------------------
extern "C" void kernel_launch(void* const* d_in, const int* in_sizes, int n_in,
                              void* d_out, int out_size, void* d_ws, size_t ws_size,
                              hipStream_t stream) {
  const float* src   = (const float*)d_in[0];
  const float* Wenc  = (const float*)d_in[1];
  const float* benc  = (const float*)d_in[2];
  const float* Wqkv  = (const float*)d_in[3];
  const float* bqkv  = (const float*)d_in[4];
  const float* Wo    = (const float*)d_in[5];
  const float* bo    = (const float*)d_in[6];
  const float* W1    = (const float*)d_in[7];
  const float* b1    = (const float*)d_in[8];
  const float* W2    = (const float*)d_in[9];
  const float* b2    = (const float*)d_in[10];
  const float* ln1s  = (const float*)d_in[11];
  const float* ln1b  = (const float*)d_in[12];
  const float* ln2s  = (const float*)d_in[13];
  const float* ln2b  = (const float*)d_in[14];
  const float* Wout  = (const float*)d_in[15];
  const float* bout  = (const float*)d_in[16];

  // ---- workspace (104 MiB total — footprint validated rounds 3/6) ----
  char* ws = (char*)d_ws;
  __hip_bfloat16* WB   = (__hip_bfloat16*)ws;      // bf16 arena (~37.3 MiB)
  __hip_bfloat16* srcb = WB;                       //   524288
  __hip_bfloat16* wenc = WB + 524288;              //    65536
  __hip_bfloat16* wqkv = WB + 589824;              //  9437184
  __hip_bfloat16* wo   = WB + 10027008;            //  3145728
  __hip_bfloat16* w1   = WB + 13172736;            //  3145728
  __hip_bfloat16* w2   = WB + 16318464;            //  3145728
  __hip_bfloat16* wout = WB + 19464192;            //    65536
  __hip_bfloat16* xb  = (__hip_bfloat16*)(ws + (size_t)40 * 1048576);  // 16 MiB
  __hip_bfloat16* qkv = (__hip_bfloat16*)(ws + (size_t)56 * 1048576);  // 48 MiB
  __hip_bfloat16* ctxp = qkv;             // q slot — attn output
  __hip_bfloat16* ybuf = qkv + H_DIM;     // k slot — (x + attn_out) / (x + ff)
  __hip_bfloat16* hbuf = qkv + 2 * H_DIM; // v slot — relu hidden temp

  const dim3 blk(256);

  // ---- ingest: all fp32 weights/src -> bf16 in ONE dispatch ----
  {
    CvtSeg s0{src,  srcb, 524288 / 4};
    CvtSeg s1{Wenc, wenc, 65536 / 4};
    CvtSeg s2{Wqkv, wqkv, 9437184 / 4};
    CvtSeg s3{Wo,   wo,   3145728 / 4};
    CvtSeg s4{W1,   w1,   3145728 / 4};
    CvtSeg s5{W2,   w2,   3145728 / 4};
    CvtSeg s6{Wout, wout, 65536 / 4};
    const int tot4 = (524288 + 65536 + 9437184 + 3 * 3145728 + 65536) / 4;
    cvt_all_k<<<dim3((tot4 + 255) / 256), blk, 0, stream>>>(s0, s1, s2, s3, s4, s5, s6);
  }

  // ---- encoder: x = src @ Wenc^T + benc   [8192,1024] (K=64 -> 1 tile) ----
  gemm_bt<0, 0, 0><<<dim3(H_DIM / 128, ROWS / 128), blk, 0, stream>>>(
      srcb, IN_DIM, wenc, benc, xb, H_DIM, nullptr, 0, ROWS, H_DIM, IN_DIM);

  for (int l = 0; l < NLAYER; l++) {
    // qkv = x @ Wqkv^T + bqkv   [8192,3072]
    gemm_bt<0, 0, 0><<<dim3(QKV_LD / 128, ROWS / 128), blk, 0, stream>>>(
        xb, H_DIM, wqkv + (size_t)l * QKV_LD * H_DIM, bqkv + l * QKV_LD,
        qkv, QKV_LD, nullptr, 0, ROWS, QKV_LD, H_DIM);
    // banded attention; ctx -> q slot
    attn_k<<<dim3(ROWS * NHEADS / 4), blk, 0, stream>>>(qkv);
    // ybuf = x + ctx @ Wo^T + bo   (residual fused in epilogue)
    gemm_bt<0, 0, 1><<<dim3(H_DIM / 128, ROWS / 128), blk, 0, stream>>>(
        ctxp, QKV_LD, wo + (size_t)l * H_DIM * H_DIM, bo + l * H_DIM,
        ybuf, QKV_LD, xb, H_DIM, ROWS, H_DIM, H_DIM);
    // x = LN(ybuf)
    ln_k<<<dim3(ROWS / 4), blk, 0, stream>>>(ybuf, QKV_LD, ln1s + l * H_DIM, ln1b + l * H_DIM, xb);
    // h = relu(x @ W1^T + b1) -> hbuf (v slot)
    gemm_bt<1, 0, 0><<<dim3(DFF_DIM / 128, ROWS / 128), blk, 0, stream>>>(
        xb, H_DIM, w1 + (size_t)l * DFF_DIM * H_DIM, b1 + l * DFF_DIM,
        hbuf, QKV_LD, nullptr, 0, ROWS, DFF_DIM, H_DIM);
    // ybuf = x + h @ W2^T + b2   (residual fused in epilogue)
    gemm_bt<0, 0, 1><<<dim3(H_DIM / 128, ROWS / 128), blk, 0, stream>>>(
        hbuf, QKV_LD, w2 + (size_t)l * H_DIM * DFF_DIM, b2 + l * H_DIM,
        ybuf, QKV_LD, xb, H_DIM, ROWS, H_DIM, DFF_DIM);
    // x = LN(ybuf)
    ln_k<<<dim3(ROWS / 4), blk, 0, stream>>>(ybuf, QKV_LD, ln2s + l * H_DIM, ln2b + l * H_DIM, xb);
  }

  // ---- decoder: out = x @ Wout^T + bout   [8192,64] FP32 OUTPUT ----
  gemm_bt<0, 1, 0><<<dim3(1, ROWS / 128), blk, 0, stream>>>(
      xb, H_DIM, wout, bout, d_out, OUT_DIM, nullptr, 0, ROWS, OUT_DIM, H_DIM);
}